// Round 1
// baseline (2618.755 us; speedup 1.0000x reference)
//
#include <hip/hip_runtime.h>

// GatherModel: 6-step NNConv message passing, reformulated:
//   agg[n,o] = sum_{k,i} S[n,k,i] * T'[k,i,o]
//   S[n] = sum_{e: dst=n} h'[e] (x) out[src[e]]     (rank-1 outer products)
//   h'[e] = [relu(e_feat@en_w1+b1), 1]              (step-invariant, bias folded)
//   T'[k,i,o] = en_w2[k, i*42+o]; T'[42,i,o] = en_b2[i*42+o]
// This turns the per-edge 42x42 matvec-with-generated-weights into a cheap
// per-edge outer product plus a per-node dense GEMM against a small constant
// tensor (303 KB, L2-resident).

#define N_NODES 10000
#define N_EDGES 160000
#define D 42
#define DE 10
#define KH 43          // 42 + bias row
#define HP 44          // h row stride (pad, 176B = 11 x float4)
#define KI 1806        // 43*42
#define SP 1808        // S / T2t row stride (pad, %4==0)
#define KC 128         // ki chunk for k_agg staging
#define NCHUNK 15      // ceil(1806/128)
#define MB 64          // nodes per WG in k_agg
#define PADS 132       // LDS row stride (floats, %4==0 for b128 alignment)

__global__ __launch_bounds__(256) void k_lin0(const float* __restrict__ nf,
        const float* __restrict__ w, const float* __restrict__ b,
        float* __restrict__ out) {
    int idx = blockIdx.x * 256 + threadIdx.x;
    if (idx >= N_NODES * D) return;
    int n = idx / D, j = idx % D;
    const float* row = nf + n * D;
    float acc = b[j];
    #pragma unroll
    for (int i = 0; i < D; ++i) acc = fmaf(row[i], w[i * D + j], acc);
    out[idx] = fmaxf(acc, 0.f);
}

__global__ __launch_bounds__(256) void k_h(const float* __restrict__ ef,
        const float* __restrict__ w1, const float* __restrict__ b1,
        float* __restrict__ h) {
    int idx = blockIdx.x * 256 + threadIdx.x;
    if (idx >= N_EDGES * HP) return;
    int e = idx / HP, j = idx % HP;
    float v;
    if (j < D) {
        const float* row = ef + e * DE;
        float acc = b1[j];
        #pragma unroll
        for (int i = 0; i < DE; ++i) acc = fmaf(row[i], w1[i * D + j], acc);
        v = fmaxf(acc, 0.f);
    } else {
        v = (j == D) ? 1.0f : 0.0f;   // bias row = 1, pad col = 0
    }
    h[idx] = v;
}

// T2t[o][ki] with ki = k*42+i: = en_w2[k*1764 + i*42 + o] (k<42), en_b2[i*42+o] (k==42)
__global__ __launch_bounds__(256) void k_T2t(const float* __restrict__ w2,
        const float* __restrict__ b2, float* __restrict__ T2t) {
    int idx = blockIdx.x * 256 + threadIdx.x;
    if (idx >= D * SP) return;
    int o = idx / SP, ki = idx % SP;
    float v = 0.f;
    if (ki < KI) {
        int k = ki / D, i = ki % D;
        v = (k < D) ? w2[k * (D * D) + i * D + o] : b2[i * D + o];
    }
    T2t[idx] = v;
}

__global__ __launch_bounds__(256) void k_hist(const int* __restrict__ dst,
        int* __restrict__ cnt) {
    int e = blockIdx.x * 256 + threadIdx.x;
    if (e < N_EDGES) atomicAdd(&cnt[dst[e]], 1);
}

// single-block exclusive scan over N_NODES counts -> row_ptr, cursor copy
__global__ __launch_bounds__(1024) void k_scan(const int* __restrict__ cnt,
        int* __restrict__ row_ptr, int* __restrict__ cursor) {
    __shared__ int buf[1024];
    __shared__ int s_run;
    const int t = threadIdx.x;
    if (t == 0) s_run = 0;
    __syncthreads();
    for (int base = 0; base < N_NODES; base += 1024) {
        int v = (base + t < N_NODES) ? cnt[base + t] : 0;
        buf[t] = v;
        __syncthreads();
        for (int off = 1; off < 1024; off <<= 1) {
            int add = (t >= off) ? buf[t - off] : 0;
            __syncthreads();
            buf[t] += add;
            __syncthreads();
        }
        int excl = buf[t] - v;
        if (base + t < N_NODES) {
            int val = s_run + excl;
            row_ptr[base + t] = val;
            cursor[base + t]  = val;
        }
        __syncthreads();
        if (t == 0) s_run += buf[1023];
        __syncthreads();
    }
    if (t == 0) { row_ptr[N_NODES] = s_run; cursor[N_NODES] = s_run; }
}

__global__ __launch_bounds__(256) void k_scatter(const int* __restrict__ dst,
        int* __restrict__ cursor, int* __restrict__ perm) {
    int e = blockIdx.x * 256 + threadIdx.x;
    if (e < N_EDGES) {
        int p = atomicAdd(&cursor[dst[e]], 1);
        perm[p] = e;
    }
}

// One wave per node: accumulate S[n] = sum_e h'[e] (x) x[e] in registers
// (44 accs/lane, lane = column i), then write the row coalesced.
__global__ __launch_bounds__(256) void k_S(
        const float* __restrict__ h, const float* __restrict__ out_in,
        const int* __restrict__ src, const int* __restrict__ row_ptr,
        const int* __restrict__ perm, float* __restrict__ S) {
    int node = blockIdx.x * 4 + (threadIdx.x >> 6);
    int l = threadIdx.x & 63;
    if (node >= N_NODES) return;
    float acc[HP];
    #pragma unroll
    for (int k = 0; k < HP; ++k) acc[k] = 0.f;
    int beg = row_ptr[node], end = row_ptr[node + 1];
    for (int ptr = beg; ptr < end; ++ptr) {
        int e = perm[ptr];                          // wave-uniform
        float x = (l < D) ? out_in[src[e] * D + l] : 0.f;
        const float4* hq = (const float4*)(h + (size_t)e * HP);  // broadcast loads
        #pragma unroll
        for (int m = 0; m < HP / 4; ++m) {
            float4 q = hq[m];
            acc[4 * m + 0] = fmaf(q.x, x, acc[4 * m + 0]);
            acc[4 * m + 1] = fmaf(q.y, x, acc[4 * m + 1]);
            acc[4 * m + 2] = fmaf(q.z, x, acc[4 * m + 2]);
            acc[4 * m + 3] = fmaf(q.w, x, acc[4 * m + 3]);
        }
    }
    if (l < D) {
        #pragma unroll
        for (int k = 0; k < KH; ++k)
            S[(size_t)node * SP + k * D + l] = acc[k];
    }
}

// agg = S @ T2t^T (register-tiled, LDS-staged), fused with node update:
//   m = relu(agg + out_in + conv_b); out' = relu(m @ msg_w + msg_b) [+ nf if last]
__global__ __launch_bounds__(256) void k_agg(
        const float* __restrict__ S, const float* __restrict__ T2t,
        const float* __restrict__ out_in, const float* __restrict__ nf,
        const float* __restrict__ msg_w, const float* __restrict__ msg_b,
        const float* __restrict__ conv_b, float* __restrict__ out_dst, int last) {
    __shared__ float smem[MB * PADS + 44 * PADS];   // 57 KB
    float* s_s  = smem;                 // [64][PADS]
    float* s_t2 = smem + MB * PADS;     // [44][PADS] (rows 42,43 zero)
    float* s_m  = smem;                 // reuse s_s region after main loop

    const int t = threadIdx.x;
    const int nbase = blockIdx.x * MB;
    const int nl = t & 63;
    const int w = t >> 6;               // wave id -> o = w + 4j
    const int n = nbase + nl;

    float acc[11];
    #pragma unroll
    for (int j = 0; j < 11; ++j) acc[j] = 0.f;

    for (int kc = 0; kc < NCHUNK; ++kc) {
        const int kbase = kc * KC;
        #pragma unroll 4
        for (int r = 0; r < (MB * KC) / 256; ++r) {      // 32 iters
            int flat = r * 256 + t;
            int n_l = flat >> 7, ki_l = flat & 127;
            int nn = nbase + n_l, ki = kbase + ki_l;
            float v = (nn < N_NODES && ki < KI) ? S[(size_t)nn * SP + ki] : 0.f;
            s_s[n_l * PADS + ki_l] = v;
        }
        #pragma unroll 4
        for (int r = 0; r < (44 * KC) / 256; ++r) {      // 22 iters
            int flat = r * 256 + t;
            int o = flat >> 7, ki_l = flat & 127;
            int ki = kbase + ki_l;
            float v = (o < D && ki < KI) ? T2t[o * SP + ki] : 0.f;
            s_t2[o * PADS + ki_l] = v;
        }
        __syncthreads();
        #pragma unroll 4
        for (int k4 = 0; k4 < KC / 4; ++k4) {
            float4 s4 = *(const float4*)&s_s[nl * PADS + k4 * 4];
            #pragma unroll
            for (int j = 0; j < 11; ++j) {
                float4 t4 = *(const float4*)&s_t2[(w + 4 * j) * PADS + k4 * 4];
                acc[j] += s4.x * t4.x + s4.y * t4.y + s4.z * t4.z + s4.w * t4.w;
            }
        }
        __syncthreads();
    }

    const int jm = (w < 2) ? 11 : 10;   // o = w+4j valid while < 42
    if (n < N_NODES) {
        for (int j = 0; j < jm; ++j) {
            int o = w + 4 * j;
            float m = acc[j] + out_in[n * D + o] + conv_b[o];
            s_m[nl * 43 + o] = fmaxf(m, 0.f);
        }
    }
    __syncthreads();
    if (n < N_NODES) {
        float a2[11];
        #pragma unroll
        for (int j = 0; j < 11; ++j) a2[j] = 0.f;
        for (int o2 = 0; o2 < D; ++o2) {
            float mv = s_m[nl * 43 + o2];
            for (int j = 0; j < jm; ++j)
                a2[j] = fmaf(mv, msg_w[o2 * D + w + 4 * j], a2[j]);
        }
        for (int j = 0; j < jm; ++j) {
            int p = w + 4 * j;
            float v = fmaxf(a2[j] + msg_b[p], 0.f);
            if (last) v += nf[n * D + p];
            out_dst[n * D + p] = v;
        }
    }
}

extern "C" void kernel_launch(void* const* d_in, const int* in_sizes, int n_in,
                              void* d_out, int out_size, void* d_ws, size_t ws_size,
                              hipStream_t stream) {
    const float* nf    = (const float*)d_in[0];
    const float* ef    = (const float*)d_in[1];
    const int*   src   = (const int*)d_in[2];
    const int*   dst   = (const int*)d_in[3];
    const float* lin0w = (const float*)d_in[4];
    const float* lin0b = (const float*)d_in[5];
    const float* msgw  = (const float*)d_in[6];
    const float* msgb  = (const float*)d_in[7];
    const float* enw1  = (const float*)d_in[8];
    const float* enb1  = (const float*)d_in[9];
    const float* enw2  = (const float*)d_in[10];
    const float* enb2  = (const float*)d_in[11];
    const float* convb = (const float*)d_in[12];

    // ws layout (~105 MB total)
    char* p = (char*)d_ws;
    auto alloc = [&](size_t bytes) -> char* {
        char* r = p; p += (bytes + 255) & ~(size_t)255; return r;
    };
    float* outA = (float*)alloc((size_t)N_NODES * D * 4);
    float* outB = (float*)alloc((size_t)N_NODES * D * 4);
    float* h    = (float*)alloc((size_t)N_EDGES * HP * 4);
    float* T2t  = (float*)alloc((size_t)D * SP * 4);
    float* Sbuf = (float*)alloc((size_t)N_NODES * SP * 4);
    int* cnt    = (int*)alloc((N_NODES + 1) * 4);
    int* rowp   = (int*)alloc((N_NODES + 1) * 4);
    int* cur    = (int*)alloc((N_NODES + 1) * 4);
    int* perm   = (int*)alloc((size_t)N_EDGES * 4);

    hipMemsetAsync(cnt, 0, (N_NODES + 1) * 4, stream);
    k_lin0<<<(N_NODES * D + 255) / 256, 256, 0, stream>>>(nf, lin0w, lin0b, outA);
    k_h<<<(N_EDGES * HP + 255) / 256, 256, 0, stream>>>(ef, enw1, enb1, h);
    k_T2t<<<(D * SP + 255) / 256, 256, 0, stream>>>(enw2, enb2, T2t);
    k_hist<<<(N_EDGES + 255) / 256, 256, 0, stream>>>(dst, cnt);
    k_scan<<<1, 1024, 0, stream>>>(cnt, rowp, cur);
    k_scatter<<<(N_EDGES + 255) / 256, 256, 0, stream>>>(dst, cur, perm);

    float* bufs[2] = {outA, outB};
    for (int s_i = 0; s_i < 6; ++s_i) {
        const float* cin = bufs[s_i % 2];
        float* cout = bufs[(s_i + 1) % 2];
        int last = (s_i == 5) ? 1 : 0;
        k_S<<<N_NODES / 4, 256, 0, stream>>>(h, cin, src, rowp, perm, Sbuf);
        k_agg<<<(N_NODES + MB - 1) / MB, 256, 0, stream>>>(
            Sbuf, T2t, cin, nf, msgw, msgb, convb,
            last ? (float*)d_out : cout, last);
    }
}

// Round 2
// 1913.528 us; speedup vs baseline: 1.3685x; 1.3685x over previous
//
#include <hip/hip_runtime.h>

// GatherModel: 6-step NNConv message passing, reformulated:
//   agg[n,o] = sum_{k,i} S[n,k,i] * T'[k,i,o]
//   S[n] = sum_{e: dst=n} h'[e] (x) out[src[e]]     (rank-1 outer products)
//   h'[e] = [relu(e_feat@en_w1+b1), 1]              (step-invariant, bias folded)
//   T'[k,i,o] = en_w2[k, i*42+o]; T'[42,i,o] = en_b2[i*42+o]
// R2: k_agg rebuilt as LDS-free K-split partial GEMM (grid 157x8) + k_node
// epilogue. R1 failure mode was grid starvation (157 WGs, 7% occupancy).

#define N_NODES 10000
#define N_EDGES 160000
#define D 42
#define DE 10
#define KH 43          // 42 + bias row
#define HP 44          // h row stride (pad, 176B = 11 x float4)
#define KI 1806        // 43*42
#define SP 1808        // S / T2t row stride (pad, %4==0)
#define KSPLIT 8
#define KRANGE 228     // per-split ki range (%4==0), 7*228+212 = 1808
#define MB 64          // nodes per WG

__global__ __launch_bounds__(256) void k_lin0(const float* __restrict__ nf,
        const float* __restrict__ w, const float* __restrict__ b,
        float* __restrict__ out) {
    int idx = blockIdx.x * 256 + threadIdx.x;
    if (idx >= N_NODES * D) return;
    int n = idx / D, j = idx % D;
    const float* row = nf + n * D;
    float acc = b[j];
    #pragma unroll
    for (int i = 0; i < D; ++i) acc = fmaf(row[i], w[i * D + j], acc);
    out[idx] = fmaxf(acc, 0.f);
}

__global__ __launch_bounds__(256) void k_h(const float* __restrict__ ef,
        const float* __restrict__ w1, const float* __restrict__ b1,
        float* __restrict__ h) {
    int idx = blockIdx.x * 256 + threadIdx.x;
    if (idx >= N_EDGES * HP) return;
    int e = idx / HP, j = idx % HP;
    float v;
    if (j < D) {
        const float* row = ef + e * DE;
        float acc = b1[j];
        #pragma unroll
        for (int i = 0; i < DE; ++i) acc = fmaf(row[i], w1[i * D + j], acc);
        v = fmaxf(acc, 0.f);
    } else {
        v = (j == D) ? 1.0f : 0.0f;   // bias row = 1, pad col = 0
    }
    h[idx] = v;
}

// T2t[o][ki] with ki = k*42+i: = en_w2[k*1764 + i*42 + o] (k<42), en_b2[i*42+o] (k==42)
__global__ __launch_bounds__(256) void k_T2t(const float* __restrict__ w2,
        const float* __restrict__ b2, float* __restrict__ T2t) {
    int idx = blockIdx.x * 256 + threadIdx.x;
    if (idx >= D * SP) return;
    int o = idx / SP, ki = idx % SP;
    float v = 0.f;
    if (ki < KI) {
        int k = ki / D, i = ki % D;
        v = (k < D) ? w2[k * (D * D) + i * D + o] : b2[i * D + o];
    }
    T2t[idx] = v;       // pad cols (1806,1807) = 0 -> padded-K loop is safe
}

__global__ __launch_bounds__(256) void k_hist(const int* __restrict__ dst,
        int* __restrict__ cnt) {
    int e = blockIdx.x * 256 + threadIdx.x;
    if (e < N_EDGES) atomicAdd(&cnt[dst[e]], 1);
}

// single-block exclusive scan over N_NODES counts -> row_ptr, cursor copy
__global__ __launch_bounds__(1024) void k_scan(const int* __restrict__ cnt,
        int* __restrict__ row_ptr, int* __restrict__ cursor) {
    __shared__ int buf[1024];
    __shared__ int s_run;
    const int t = threadIdx.x;
    if (t == 0) s_run = 0;
    __syncthreads();
    for (int base = 0; base < N_NODES; base += 1024) {
        int v = (base + t < N_NODES) ? cnt[base + t] : 0;
        buf[t] = v;
        __syncthreads();
        for (int off = 1; off < 1024; off <<= 1) {
            int add = (t >= off) ? buf[t - off] : 0;
            __syncthreads();
            buf[t] += add;
            __syncthreads();
        }
        int excl = buf[t] - v;
        if (base + t < N_NODES) {
            int val = s_run + excl;
            row_ptr[base + t] = val;
            cursor[base + t]  = val;
        }
        __syncthreads();
        if (t == 0) s_run += buf[1023];
        __syncthreads();
    }
    if (t == 0) { row_ptr[N_NODES] = s_run; cursor[N_NODES] = s_run; }
}

__global__ __launch_bounds__(256) void k_scatter(const int* __restrict__ dst,
        int* __restrict__ cursor, int* __restrict__ perm) {
    int e = blockIdx.x * 256 + threadIdx.x;
    if (e < N_EDGES) {
        int p = atomicAdd(&cursor[dst[e]], 1);
        perm[p] = e;
    }
}

// One wave per node: accumulate S[n] = sum_e h'[e] (x) x[e] in registers
// (44 accs/lane, lane = column i), then write the row coalesced.
__global__ __launch_bounds__(256) void k_S(
        const float* __restrict__ h, const float* __restrict__ out_in,
        const int* __restrict__ src, const int* __restrict__ row_ptr,
        const int* __restrict__ perm, float* __restrict__ S) {
    int node = blockIdx.x * 4 + (threadIdx.x >> 6);
    int l = threadIdx.x & 63;
    if (node >= N_NODES) return;
    float acc[HP];
    #pragma unroll
    for (int k = 0; k < HP; ++k) acc[k] = 0.f;
    int beg = row_ptr[node], end = row_ptr[node + 1];
    for (int ptr = beg; ptr < end; ++ptr) {
        int e = perm[ptr];                          // wave-uniform
        float x = (l < D) ? out_in[src[e] * D + l] : 0.f;
        const float4* hq = (const float4*)(h + (size_t)e * HP);  // broadcast loads
        #pragma unroll
        for (int m = 0; m < HP / 4; ++m) {
            float4 q = hq[m];
            acc[4 * m + 0] = fmaf(q.x, x, acc[4 * m + 0]);
            acc[4 * m + 1] = fmaf(q.y, x, acc[4 * m + 1]);
            acc[4 * m + 2] = fmaf(q.z, x, acc[4 * m + 2]);
            acc[4 * m + 3] = fmaf(q.w, x, acc[4 * m + 3]);
        }
    }
    if (l < D) {
        #pragma unroll
        for (int k = 0; k < KH; ++k)
            S[(size_t)node * SP + k * D + l] = acc[k];
    } else if (l < D + 2) {
        S[(size_t)node * SP + KI + (l - D)] = 0.f;  // zero the 2 pad floats
    }
}

// Partial GEMM: aggP[ks][n][o] = sum_{ki in split ks} S[n][ki] * T2t[o][ki]
// LDS-free: S via per-lane float4 (L1-reused), T2t via wave-uniform broadcast.
__global__ __launch_bounds__(256) void k_agg_part(
        const float* __restrict__ S, const float* __restrict__ T2t,
        float* __restrict__ aggP) {
    const int nl = threadIdx.x & 63;
    const int w  = threadIdx.x >> 6;            // o = w + 4j
    const int n  = blockIdx.x * MB + nl;
    if (n >= N_NODES) return;
    const int kbeg = blockIdx.y * KRANGE;
    const int kend = min(kbeg + KRANGE, SP);    // pad cols are S=0*T=0

    float acc[11];
    #pragma unroll
    for (int j = 0; j < 11; ++j) acc[j] = 0.f;
    const int jm = (w < 2) ? 11 : 10;           // o = w+4j < 42

    const float* srow = S + (size_t)n * SP;
    #pragma unroll 2
    for (int ki = kbeg; ki < kend; ki += 4) {
        float4 s4 = *(const float4*)(srow + ki);
        for (int j = 0; j < jm; ++j) {
            float4 t4 = *(const float4*)(T2t + (w + 4 * j) * SP + ki);
            acc[j] += s4.x * t4.x + s4.y * t4.y + s4.z * t4.z + s4.w * t4.w;
        }
    }
    float* dst = aggP + (size_t)blockIdx.y * (N_NODES * D) + (size_t)n * D;
    for (int j = 0; j < jm; ++j) dst[w + 4 * j] = acc[j];
}

// Epilogue: agg = sum_ks aggP; m = relu(agg + out_in + conv_b);
// out' = relu(m @ msg_w + msg_b) [+ nf if last]
__global__ __launch_bounds__(256) void k_node(
        const float* __restrict__ aggP, const float* __restrict__ out_in,
        const float* __restrict__ nf, const float* __restrict__ msg_w,
        const float* __restrict__ msg_b, const float* __restrict__ conv_b,
        float* __restrict__ out_dst, int last) {
    __shared__ float s_m[MB * 44];
    const int nl = threadIdx.x & 63;
    const int w  = threadIdx.x >> 6;
    const int n  = blockIdx.x * MB + nl;
    const int jm = (w < 2) ? 11 : 10;

    if (n < N_NODES) {
        for (int j = 0; j < jm; ++j) {
            int o = w + 4 * j;
            float a = 0.f;
            #pragma unroll
            for (int ks = 0; ks < KSPLIT; ++ks)
                a += aggP[(size_t)ks * (N_NODES * D) + (size_t)n * D + o];
            float m = a + out_in[n * D + o] + conv_b[o];
            s_m[nl * 44 + o] = fmaxf(m, 0.f);
        }
    }
    __syncthreads();
    if (n < N_NODES) {
        float a2[11];
        #pragma unroll
        for (int j = 0; j < 11; ++j) a2[j] = 0.f;
        for (int o2 = 0; o2 < D; ++o2) {
            float mv = s_m[nl * 44 + o2];
            for (int j = 0; j < jm; ++j)
                a2[j] = fmaf(mv, msg_w[o2 * D + w + 4 * j], a2[j]);
        }
        for (int j = 0; j < jm; ++j) {
            int p = w + 4 * j;
            float v = fmaxf(a2[j] + msg_b[p], 0.f);
            if (last) v += nf[n * D + p];
            out_dst[n * D + p] = v;
        }
    }
}

extern "C" void kernel_launch(void* const* d_in, const int* in_sizes, int n_in,
                              void* d_out, int out_size, void* d_ws, size_t ws_size,
                              hipStream_t stream) {
    const float* nf    = (const float*)d_in[0];
    const float* ef    = (const float*)d_in[1];
    const int*   src   = (const int*)d_in[2];
    const int*   dst   = (const int*)d_in[3];
    const float* lin0w = (const float*)d_in[4];
    const float* lin0b = (const float*)d_in[5];
    const float* msgw  = (const float*)d_in[6];
    const float* msgb  = (const float*)d_in[7];
    const float* enw1  = (const float*)d_in[8];
    const float* enb1  = (const float*)d_in[9];
    const float* enw2  = (const float*)d_in[10];
    const float* enb2  = (const float*)d_in[11];
    const float* convb = (const float*)d_in[12];

    // ws layout (~119 MB total)
    char* p = (char*)d_ws;
    auto alloc = [&](size_t bytes) -> char* {
        char* r = p; p += (bytes + 255) & ~(size_t)255; return r;
    };
    float* outA = (float*)alloc((size_t)N_NODES * D * 4);
    float* outB = (float*)alloc((size_t)N_NODES * D * 4);
    float* h    = (float*)alloc((size_t)N_EDGES * HP * 4);
    float* T2t  = (float*)alloc((size_t)D * SP * 4);
    float* Sbuf = (float*)alloc((size_t)N_NODES * SP * 4);
    float* aggP = (float*)alloc((size_t)KSPLIT * N_NODES * D * 4);
    int* cnt    = (int*)alloc((N_NODES + 1) * 4);
    int* rowp   = (int*)alloc((N_NODES + 1) * 4);
    int* cur    = (int*)alloc((N_NODES + 1) * 4);
    int* perm   = (int*)alloc((size_t)N_EDGES * 4);

    hipMemsetAsync(cnt, 0, (N_NODES + 1) * 4, stream);
    k_lin0<<<(N_NODES * D + 255) / 256, 256, 0, stream>>>(nf, lin0w, lin0b, outA);
    k_h<<<(N_EDGES * HP + 255) / 256, 256, 0, stream>>>(ef, enw1, enb1, h);
    k_T2t<<<(D * SP + 255) / 256, 256, 0, stream>>>(enw2, enb2, T2t);
    k_hist<<<(N_EDGES + 255) / 256, 256, 0, stream>>>(dst, cnt);
    k_scan<<<1, 1024, 0, stream>>>(cnt, rowp, cur);
    k_scatter<<<(N_EDGES + 255) / 256, 256, 0, stream>>>(dst, cur, perm);

    const int ntiles = (N_NODES + MB - 1) / MB;   // 157
    float* bufs[2] = {outA, outB};
    for (int s_i = 0; s_i < 6; ++s_i) {
        const float* cin = bufs[s_i % 2];
        float* cout = bufs[(s_i + 1) % 2];
        int last = (s_i == 5) ? 1 : 0;
        k_S<<<N_NODES / 4, 256, 0, stream>>>(h, cin, src, rowp, perm, Sbuf);
        k_agg_part<<<dim3(ntiles, KSPLIT), 256, 0, stream>>>(Sbuf, T2t, aggP);
        k_node<<<ntiles, 256, 0, stream>>>(aggP, cin, nf, msgw, msgb, convb,
                                           last ? (float*)d_out : cout, last);
    }
}